// Round 1
// baseline (625.047 us; speedup 1.0000x reference)
//
#include <hip/hip_runtime.h>
#include <stdint.h>

typedef unsigned short u16;
typedef u16 u16x8 __attribute__((ext_vector_type(8)));
typedef __bf16 bf16x8 __attribute__((ext_vector_type(8)));
typedef float f32x4 __attribute__((ext_vector_type(4)));

#define DEV static __device__ __forceinline__

DEV u16 f2bf(float f) {
  union { float f; uint32_t u; } v; v.f = f;
  uint32_t r = v.u + 0x7FFFu + ((v.u >> 16) & 1u);
  return (u16)(r >> 16);
}
DEV float bf2f(u16 s) {
  union { uint32_t u; float f; } v; v.u = ((uint32_t)s) << 16;
  return v.f;
}
DEV float elu1(float x) { return x > 0.f ? x + 1.f : __expf(x); }
DEV u16x8 ld8u(const u16* p) { return *reinterpret_cast<const u16x8*>(p); }

DEV f32x4 mfma16(u16x8 a, u16x8 b, f32x4 c) {
  return __builtin_amdgcn_mfma_f32_16x16x32_bf16(
      __builtin_bit_cast(bf16x8, a), __builtin_bit_cast(bf16x8, b), c, 0, 0, 0);
}
DEV void async16(void* lds, const void* g) {
  __builtin_amdgcn_global_load_lds(
      (__attribute__((address_space(1))) void*)g,
      (__attribute__((address_space(3))) void*)lds, 16, 0, 0);
}

// ---------------- prep kernels ----------------

__global__ __launch_bounds__(256) void k_cvt(const float* __restrict__ in, u16* __restrict__ out) {
  int i = blockIdx.x * 256 + threadIdx.x;  // 8192*256 threads, 8 elems each
  const float4* p = reinterpret_cast<const float4*>(in) + (size_t)i * 2;
  float4 a = p[0], b = p[1];
  u16x8 o;
  o[0] = f2bf(a.x); o[1] = f2bf(a.y); o[2] = f2bf(a.z); o[3] = f2bf(a.w);
  o[4] = f2bf(b.x); o[5] = f2bf(b.y); o[6] = f2bf(b.z); o[7] = f2bf(b.w);
  reinterpret_cast<u16x8*>(out)[i] = o;
}

__global__ __launch_bounds__(1024) void k_tr(const float* __restrict__ Wq, const float* __restrict__ Wk,
                                             const float* __restrict__ Wv, const float* __restrict__ Wo,
                                             u16* __restrict__ wt, u16* __restrict__ wot) {
  __shared__ float tb[32][33];
  int mat = blockIdx.x >> 10;
  int tile = blockIdx.x & 1023;
  int n0 = (tile >> 5) * 32;
  int k0 = (tile & 31) * 32;
  const float* W = (mat == 0) ? Wq : (mat == 1) ? Wk : (mat == 2) ? Wv : Wo;
  int tx = threadIdx.x & 31, ty = threadIdx.x >> 5;
  tb[ty][tx] = W[(size_t)(k0 + ty) * 1024 + n0 + tx];
  __syncthreads();
  u16 v = f2bf(tb[tx][ty]);  // = W[k0+tx][n0+ty]
  if (mat < 3) wt[(size_t)(mat * 1024 + n0 + ty) * 1024 + k0 + tx] = v;
  else         wot[(size_t)(n0 + ty) * 1024 + k0 + tx] = v;
}

__global__ void k_bias(const float* __restrict__ rel, float* __restrict__ bias) {
  int off = blockIdx.x * 256 + threadIdx.x;
  if (off >= 1023) return;
  int rp = off - 511;                 // relative position j - i
  int bck = rp > 0 ? 16 : 0;
  int arp = rp < 0 ? -rp : rp;
  int idx;
  if (arp < 8) idx = arp;
  else {
    float l = logf((float)arp * 0.125f) / logf(16.0f) * 8.0f;
    int lg = 8 + (int)l;
    idx = lg < 15 ? lg : 15;
  }
  bck += idx;
  for (int h = 0; h < 16; ++h) bias[h * 1023 + off] = rel[bck * 16 + h];
}

// ---------------- MFMA GEMM (128x128 tile, BK=64, 4 waves) ----------------
// EPI=0: C = hs @ [Wq|Wk|Wv] -> scatter to Q(b,h,s,d), K(b,h,s,d), Vt(b,h,d,s) bf16
// EPI=1: C = blend @ Wo -> fp32 out

template <int EPI>
__global__ __launch_bounds__(256) void k_gemm(const u16* __restrict__ A, const u16* __restrict__ Bt,
                                              u16* __restrict__ oq, u16* __restrict__ ok2,
                                              u16* __restrict__ ovt, float* __restrict__ of) {
  __shared__ __align__(16) u16 lA[128 * 64];
  __shared__ __align__(16) u16 lB[128 * 64];
  const int t = threadIdx.x;
  const int m0 = blockIdx.x * 128;
  const int n0 = blockIdx.y * 128;
  const int lane = t & 63;
  const int w = t >> 6, wm = w >> 1, wn = w & 1;
  const int lr = lane & 15, lg = lane >> 4;

  f32x4 acc[4][4];
#pragma unroll
  for (int i = 0; i < 4; ++i)
#pragma unroll
    for (int j = 0; j < 4; ++j) acc[i][j] = (f32x4){0.f, 0.f, 0.f, 0.f};

  const u16* pa = A + (size_t)(m0 + (t >> 3)) * 1024 + (t & 7) * 8;
  const u16* pb = Bt + (size_t)(n0 + (t >> 3)) * 1024 + (t & 7) * 8;
  u16* la = lA + t * 8;
  u16* lb = lB + t * 8;

  for (int k0 = 0; k0 < 1024; k0 += 64) {
#pragma unroll
    for (int i = 0; i < 4; ++i) {
      async16(la + i * 2048, pa + (size_t)i * 32 * 1024 + k0);
      async16(lb + i * 2048, pb + (size_t)i * 32 * 1024 + k0);
    }
    __syncthreads();
#pragma unroll
    for (int kk = 0; kk < 2; ++kk) {
      u16x8 af[4], bfv[4];
#pragma unroll
      for (int mi = 0; mi < 4; ++mi) af[mi] = ld8u(lA + (wm * 64 + mi * 16 + lr) * 64 + kk * 32 + lg * 8);
#pragma unroll
      for (int ni = 0; ni < 4; ++ni) bfv[ni] = ld8u(lB + (wn * 64 + ni * 16 + lr) * 64 + kk * 32 + lg * 8);
#pragma unroll
      for (int mi = 0; mi < 4; ++mi)
#pragma unroll
        for (int ni = 0; ni < 4; ++ni) acc[mi][ni] = mfma16(af[mi], bfv[ni], acc[mi][ni]);
    }
    __syncthreads();
  }

  if (EPI == 0) {
    const int which = n0 >> 10;
    const int nb = (n0 & 1023) + wn * 64;
#pragma unroll
    for (int mi = 0; mi < 4; ++mi)
#pragma unroll
      for (int r = 0; r < 4; ++r) {
        int m = m0 + wm * 64 + mi * 16 + lg * 4 + r;
        int b = m >> 9, s = m & 511;
#pragma unroll
        for (int ni = 0; ni < 4; ++ni) {
          int nc = nb + ni * 16 + lr;
          int h = nc >> 6, d = nc & 63;
          int bh = b * 16 + h;
          u16 v = f2bf(acc[mi][ni][r]);
          if (which == 0)      oq[(size_t)(bh * 512 + s) * 64 + d] = v;
          else if (which == 1) ok2[(size_t)(bh * 512 + s) * 64 + d] = v;
          else                 ovt[(size_t)(bh * 64 + d) * 512 + s] = v;
        }
      }
  } else {
#pragma unroll
    for (int mi = 0; mi < 4; ++mi)
#pragma unroll
      for (int r = 0; r < 4; ++r) {
        int m = m0 + wm * 64 + mi * 16 + lg * 4 + r;
#pragma unroll
        for (int ni = 0; ni < 4; ++ni) {
          int n = n0 + wn * 64 + ni * 16 + lr;
          of[(size_t)m * 1024 + n] = acc[mi][ni][r];
        }
      }
  }
}

// ---------------- compressive memory: partial M, z per (g,h,c) ----------------

__global__ __launch_bounds__(256) void k_mem(const u16* __restrict__ K, const u16* __restrict__ Vt,
                                             float* __restrict__ Mp, float* __restrict__ zp) {
  __shared__ __align__(16) float sk[128 * 64];
  __shared__ __align__(16) float vv[128 * 64];
  const int bid = blockIdx.x;  // ((g*16+h)*8 + c)
  const int g = bid >> 7, h = (bid >> 3) & 15, c = bid & 7;
  const int bh = (g * 8 + c) * 16 + h;
  const u16* kp = K + (size_t)bh * 512 * 64;
  const u16* vp = Vt + (size_t)bh * 64 * 512;
  const int t = threadIdx.x;
  const int d = t & 63, eg = t >> 6;
  float acc[16];
#pragma unroll
  for (int j = 0; j < 16; ++j) acc[j] = 0.f;
  float zacc = 0.f;

  for (int s0 = 0; s0 < 512; s0 += 128) {
    __syncthreads();
    for (int j = 0; j < 32; ++j) {
      int idx = j * 256 + t;
      int ss = idx >> 6, dd = idx & 63;
      sk[idx] = elu1(bf2f(kp[(size_t)(s0 + ss) * 64 + dd]));
      int ee = idx >> 7, s2 = idx & 127;
      vv[s2 * 64 + ee] = bf2f(vp[(size_t)ee * 512 + s0 + s2]);
    }
    __syncthreads();
    for (int ss = 0; ss < 128; ++ss) {
      float a = sk[ss * 64 + d];
      if (eg == 0) zacc += a;
      const f32x4* vr = reinterpret_cast<const f32x4*>(&vv[ss * 64 + eg * 16]);
#pragma unroll
      for (int j4 = 0; j4 < 4; ++j4) {
        f32x4 vq = vr[j4];
        acc[j4 * 4 + 0] += a * vq[0];
        acc[j4 * 4 + 1] += a * vq[1];
        acc[j4 * 4 + 2] += a * vq[2];
        acc[j4 * 4 + 3] += a * vq[3];
      }
    }
  }
  float* mp = Mp + (size_t)bid * 4096 + d * 64 + eg * 16;
#pragma unroll
  for (int j = 0; j < 16; ++j) mp[j] = acc[j];
  if (eg == 0) zp[(size_t)bid * 64 + d] = zacc;
}

__global__ __launch_bounds__(256) void k_red(const float* __restrict__ Mp, const float* __restrict__ zp,
                                             u16* __restrict__ Mt, float* __restrict__ zv) {
  const int gh = blockIdx.x;
  const int t = threadIdx.x;
#pragma unroll
  for (int j = 0; j < 16; ++j) {
    int idx = j * 256 + t;
    int d = idx >> 6, e = idx & 63;
    float s = 0.f;
#pragma unroll
    for (int c = 0; c < 8; ++c) s += Mp[(size_t)(gh * 8 + c) * 4096 + idx];
    Mt[(size_t)gh * 4096 + e * 64 + d] = f2bf(s);  // transposed (e,d) for MFMA B-frag
  }
  if (t < 64) {
    float s = 0.f;
#pragma unroll
    for (int c = 0; c < 8; ++c) s += zp[(size_t)(gh * 8 + c) * 64 + t];
    zv[gh * 64 + t] = s;
  }
}

// ---------------- fused attention + compressive blend, one block per (b,h) ----------------

__global__ __launch_bounds__(256) void k_attn(const u16* __restrict__ Q, const u16* __restrict__ K,
                                              const u16* __restrict__ Vt, const u16* __restrict__ Mt,
                                              const float* __restrict__ zv, const float* __restrict__ bias,
                                              const float* __restrict__ beta, u16* __restrict__ blend) {
  __shared__ __align__(16) u16 ps[64][520];  // exp(scores) bf16, padded stride (16B aligned rows)
  __shared__ float dens[64];
  __shared__ float zs[64];
  const int bid = blockIdx.x;  // b*16 + h
  const int b = bid >> 4, h = bid & 15, g = b >> 3;
  const int gh = g * 16 + h;
  const int t = threadIdx.x, lane = t & 63, w = t >> 6;
  const int lr = lane & 15, lg = lane >> 4;
  const u16* qp = Q + (size_t)bid * 512 * 64;
  const u16* kp = K + (size_t)bid * 512 * 64;
  const u16* vp = Vt + (size_t)bid * 64 * 512;
  const u16* mp = Mt + (size_t)gh * 4096;
  const float* bh_ = bias + h * 1023;
  const float gate = 1.f / (1.f + __expf(-beta[h]));
  if (t < 64) zs[t] = zv[gh * 64 + t];
  __syncthreads();

  for (int qt = 0; qt < 8; ++qt) {
    // den[row] = sum_d (elu(q)+1) * z[d] + 1e-6   (wave 0, one row per thread)
    if (t < 64) {
      int rg = qt * 64 + t;
      float sum = 0.f;
#pragma unroll
      for (int d8 = 0; d8 < 8; ++d8) {
        u16x8 v = ld8u(qp + (size_t)rg * 64 + d8 * 8);
#pragma unroll
        for (int j = 0; j < 8; ++j) sum += elu1(bf2f(v[j])) * zs[d8 * 8 + j];
      }
      dens[t] = sum + 1e-6f;
    }
    // pass 1: QK^T + bias -> P = exp(score) (no max-sub needed; |score| < ~24)
    const int qrow = qt * 64 + w * 16 + lr;
    u16x8 aq0 = ld8u(qp + (size_t)qrow * 64 + lg * 8);
    u16x8 aq1 = ld8u(qp + (size_t)qrow * 64 + 32 + lg * 8);
    float lreg[4] = {0.f, 0.f, 0.f, 0.f};
    const int ibase = qt * 64 + w * 16 + lg * 4;
#pragma unroll 4
    for (int ni = 0; ni < 32; ++ni) {
      const int kpos = ni * 16 + lr;
      f32x4 sa = (f32x4){0.f, 0.f, 0.f, 0.f};
      sa = mfma16(aq0, ld8u(kp + (size_t)kpos * 64 + lg * 8), sa);
      sa = mfma16(aq1, ld8u(kp + (size_t)kpos * 64 + 32 + lg * 8), sa);
#pragma unroll
      for (int r = 0; r < 4; ++r) {
        float sc = sa[r] + bh_[kpos - (ibase + r) + 511];
        float p = __expf(sc);
        lreg[r] += p;
        ps[w * 16 + lg * 4 + r][kpos] = f2bf(p);
      }
    }
    float rl[4];
#pragma unroll
    for (int r = 0; r < 4; ++r) {
      float v = lreg[r];
      v += __shfl_xor(v, 1, 64);
      v += __shfl_xor(v, 2, 64);
      v += __shfl_xor(v, 4, 64);
      v += __shfl_xor(v, 8, 64);
      rl[r] = 1.f / v;
    }
    __syncthreads();
    // pass 2: PV + sq@Mt + blend
    f32x4 accd[4], accm[4];
#pragma unroll
    for (int ni = 0; ni < 4; ++ni) { accd[ni] = (f32x4){0.f,0.f,0.f,0.f}; accm[ni] = (f32x4){0.f,0.f,0.f,0.f}; }
#pragma unroll 4
    for (int kk = 0; kk < 16; ++kk) {
      u16x8 ap = ld8u(&ps[w * 16 + lr][kk * 32 + lg * 8]);
#pragma unroll
      for (int ni = 0; ni < 4; ++ni)
        accd[ni] = mfma16(ap, ld8u(vp + (size_t)(ni * 16 + lr) * 512 + kk * 32 + lg * 8), accd[ni]);
    }
    u16x8 sq0, sq1;
#pragma unroll
    for (int j = 0; j < 8; ++j) { sq0[j] = f2bf(elu1(bf2f(aq0[j]))); sq1[j] = f2bf(elu1(bf2f(aq1[j]))); }
#pragma unroll
    for (int ni = 0; ni < 4; ++ni) {
      accm[ni] = mfma16(sq0, ld8u(mp + (ni * 16 + lr) * 64 + lg * 8), accm[ni]);
      accm[ni] = mfma16(sq1, ld8u(mp + (ni * 16 + lr) * 64 + 32 + lg * 8), accm[ni]);
    }
#pragma unroll
    for (int ni = 0; ni < 4; ++ni)
#pragma unroll
      for (int r = 0; r < 4; ++r) {
        int rowl = w * 16 + lg * 4 + r;
        float adot = accd[ni][r] * rl[r];
        float amem = accm[ni][r] / dens[rowl];
        float o = gate * amem + (1.f - gate) * adot;
        int sg = qt * 64 + rowl;
        blend[(size_t)(b * 512 + sg) * 1024 + h * 64 + ni * 16 + lr] = f2bf(o);
      }
    __syncthreads();
  }
}

// ---------------- launch ----------------

extern "C" void kernel_launch(void* const* d_in, const int* in_sizes, int n_in,
                              void* d_out, int out_size, void* d_ws, size_t ws_size,
                              hipStream_t stream) {
  (void)in_sizes; (void)n_in; (void)out_size; (void)ws_size;
  const float* hs   = (const float*)d_in[0];
  const float* Wq   = (const float*)d_in[1];
  const float* Wk   = (const float*)d_in[2];
  const float* Wv   = (const float*)d_in[3];
  const float* Wo   = (const float*)d_in[4];
  const float* rel  = (const float*)d_in[5];
  const float* beta = (const float*)d_in[6];
  float* out = (float*)d_out;

  char* ws = (char*)d_ws;
  size_t off = 0;
  auto alloc = [&](size_t bytes) -> char* {
    char* p = ws + off;
    off += (bytes + 255) & ~(size_t)255;
    return p;
  };
  u16* hsb    = (u16*)alloc(16384ull * 1024 * 2);  // reused as blend after GEMM1
  u16* wt     = (u16*)alloc(3072ull * 1024 * 2);
  u16* wot    = (u16*)alloc(1024ull * 1024 * 2);
  u16* q      = (u16*)alloc(16384ull * 1024 * 2);
  u16* k      = (u16*)alloc(16384ull * 1024 * 2);
  u16* vt     = (u16*)alloc(16384ull * 1024 * 2);
  float* Mp   = (float*)alloc(512ull * 4096 * 4);
  float* zp   = (float*)alloc(512ull * 64 * 4);
  u16* Mt     = (u16*)alloc(64ull * 4096 * 2);
  float* zv   = (float*)alloc(64ull * 64 * 4);
  float* bias = (float*)alloc(16ull * 1023 * 4);
  u16* blend  = hsb;

  k_cvt<<<8192, 256, 0, stream>>>(hs, hsb);
  k_tr<<<4096, 1024, 0, stream>>>(Wq, Wk, Wv, Wo, wt, wot);
  k_bias<<<4, 256, 0, stream>>>(rel, bias);
  k_gemm<0><<<dim3(128, 24), 256, 0, stream>>>(hsb, wt, q, k, vt, nullptr);
  k_mem<<<512, 256, 0, stream>>>(k, vt, Mp, zp);
  k_red<<<64, 256, 0, stream>>>(Mp, zp, Mt, zv);
  k_attn<<<512, 256, 0, stream>>>(q, k, vt, Mt, zv, bias, beta, blend);
  k_gemm<1><<<dim3(128, 8), 256, 0, stream>>>(blend, wot, nullptr, nullptr, nullptr, out);
}

// Round 2
// 439.642 us; speedup vs baseline: 1.4217x; 1.4217x over previous
//
#include <hip/hip_runtime.h>
#include <stdint.h>

typedef unsigned short u16;
typedef u16 u16x8 __attribute__((ext_vector_type(8)));
typedef u16 u16x4 __attribute__((ext_vector_type(4)));
typedef __bf16 bf16x8 __attribute__((ext_vector_type(8)));
typedef float f32x4 __attribute__((ext_vector_type(4)));

#define DEV static __device__ __forceinline__

DEV u16 f2bf(float f) {
  union { float f; uint32_t u; } v; v.f = f;
  uint32_t r = v.u + 0x7FFFu + ((v.u >> 16) & 1u);
  return (u16)(r >> 16);
}
DEV float bf2f(u16 s) {
  union { uint32_t u; float f; } v; v.u = ((uint32_t)s) << 16;
  return v.f;
}
DEV float elu1(float x) { return x > 0.f ? x + 1.f : __expf(x); }
DEV u16x8 ld8u(const u16* p) { return *reinterpret_cast<const u16x8*>(p); }

DEV f32x4 mfma16(u16x8 a, u16x8 b, f32x4 c) {
  return __builtin_amdgcn_mfma_f32_16x16x32_bf16(
      __builtin_bit_cast(bf16x8, a), __builtin_bit_cast(bf16x8, b), c, 0, 0, 0);
}
DEV void async16(void* lds, const void* g) {
  __builtin_amdgcn_global_load_lds(
      (__attribute__((address_space(1))) void*)g,
      (__attribute__((address_space(3))) void*)lds, 16, 0, 0);
}

// ---------------- prep kernels ----------------

__global__ __launch_bounds__(256) void k_cvt(const float* __restrict__ in, u16* __restrict__ out) {
  int i = blockIdx.x * 256 + threadIdx.x;
  const float4* p = reinterpret_cast<const float4*>(in) + (size_t)i * 2;
  float4 a = p[0], b = p[1];
  u16x8 o;
  o[0] = f2bf(a.x); o[1] = f2bf(a.y); o[2] = f2bf(a.z); o[3] = f2bf(a.w);
  o[4] = f2bf(b.x); o[5] = f2bf(b.y); o[6] = f2bf(b.z); o[7] = f2bf(b.w);
  reinterpret_cast<u16x8*>(out)[i] = o;
}

__global__ __launch_bounds__(1024) void k_tr(const float* __restrict__ Wq, const float* __restrict__ Wk,
                                             const float* __restrict__ Wv, const float* __restrict__ Wo,
                                             u16* __restrict__ wt, u16* __restrict__ wot) {
  __shared__ float tb[32][33];
  int mat = blockIdx.x >> 10;
  int tile = blockIdx.x & 1023;
  int n0 = (tile >> 5) * 32;
  int k0 = (tile & 31) * 32;
  const float* W = (mat == 0) ? Wq : (mat == 1) ? Wk : (mat == 2) ? Wv : Wo;
  int tx = threadIdx.x & 31, ty = threadIdx.x >> 5;
  tb[ty][tx] = W[(size_t)(k0 + ty) * 1024 + n0 + tx];
  __syncthreads();
  u16 v = f2bf(tb[tx][ty]);
  if (mat < 3) wt[(size_t)(mat * 1024 + n0 + ty) * 1024 + k0 + tx] = v;
  else         wot[(size_t)(n0 + ty) * 1024 + k0 + tx] = v;
}

__global__ void k_bias(const float* __restrict__ rel, float* __restrict__ bias) {
  int off = blockIdx.x * 256 + threadIdx.x;
  if (off >= 1023) return;
  int rp = off - 511;
  int bck = rp > 0 ? 16 : 0;
  int arp = rp < 0 ? -rp : rp;
  int idx;
  if (arp < 8) idx = arp;
  else {
    float l = logf((float)arp * 0.125f) / logf(16.0f) * 8.0f;
    int lg = 8 + (int)l;
    idx = lg < 15 ? lg : 15;
  }
  bck += idx;
  for (int h = 0; h < 16; ++h) bias[h * 1023 + off] = rel[bck * 16 + h];
}

// ---------------- MFMA GEMM (128x128 tile, BK=64, 4 waves) ----------------

template <int EPI>
__global__ __launch_bounds__(256) void k_gemm(const u16* __restrict__ A, const u16* __restrict__ Bt,
                                              u16* __restrict__ oq, u16* __restrict__ ok2,
                                              u16* __restrict__ ovt, float* __restrict__ of) {
  __shared__ __align__(16) u16 lA[128 * 64];
  __shared__ __align__(16) u16 lB[128 * 64];
  const int t = threadIdx.x;
  const int m0 = blockIdx.x * 128;
  const int n0 = blockIdx.y * 128;
  const int lane = t & 63;
  const int w = t >> 6, wm = w >> 1, wn = w & 1;
  const int lr = lane & 15, lg = lane >> 4;

  f32x4 acc[4][4];
#pragma unroll
  for (int i = 0; i < 4; ++i)
#pragma unroll
    for (int j = 0; j < 4; ++j) acc[i][j] = (f32x4){0.f, 0.f, 0.f, 0.f};

  const u16* pa = A + (size_t)(m0 + (t >> 3)) * 1024 + (t & 7) * 8;
  const u16* pb = Bt + (size_t)(n0 + (t >> 3)) * 1024 + (t & 7) * 8;
  u16* la = lA + t * 8;
  u16* lb = lB + t * 8;

  for (int k0 = 0; k0 < 1024; k0 += 64) {
#pragma unroll
    for (int i = 0; i < 4; ++i) {
      async16(la + i * 2048, pa + (size_t)i * 32 * 1024 + k0);
      async16(lb + i * 2048, pb + (size_t)i * 32 * 1024 + k0);
    }
    __syncthreads();
#pragma unroll
    for (int kk = 0; kk < 2; ++kk) {
      u16x8 af[4], bfv[4];
#pragma unroll
      for (int mi = 0; mi < 4; ++mi) af[mi] = ld8u(lA + (wm * 64 + mi * 16 + lr) * 64 + kk * 32 + lg * 8);
#pragma unroll
      for (int ni = 0; ni < 4; ++ni) bfv[ni] = ld8u(lB + (wn * 64 + ni * 16 + lr) * 64 + kk * 32 + lg * 8);
#pragma unroll
      for (int mi = 0; mi < 4; ++mi)
#pragma unroll
        for (int ni = 0; ni < 4; ++ni) acc[mi][ni] = mfma16(af[mi], bfv[ni], acc[mi][ni]);
    }
    __syncthreads();
  }

  if (EPI == 0) {
    const int which = n0 >> 10;
    const int nb = (n0 & 1023) + wn * 64;
#pragma unroll
    for (int mi = 0; mi < 4; ++mi)
#pragma unroll
      for (int r = 0; r < 4; ++r) {
        int m = m0 + wm * 64 + mi * 16 + lg * 4 + r;
        int b = m >> 9, s = m & 511;
#pragma unroll
        for (int ni = 0; ni < 4; ++ni) {
          int nc = nb + ni * 16 + lr;
          int h = nc >> 6, d = nc & 63;
          int bh = b * 16 + h;
          u16 v = f2bf(acc[mi][ni][r]);
          if (which == 0)      oq[(size_t)(bh * 512 + s) * 64 + d] = v;
          else if (which == 1) ok2[(size_t)(bh * 512 + s) * 64 + d] = v;
          else                 ovt[(size_t)(bh * 64 + d) * 512 + s] = v;
        }
      }
  } else {
#pragma unroll
    for (int mi = 0; mi < 4; ++mi)
#pragma unroll
      for (int r = 0; r < 4; ++r) {
        int m = m0 + wm * 64 + mi * 16 + lg * 4 + r;
#pragma unroll
        for (int ni = 0; ni < 4; ++ni) {
          int n = n0 + wn * 64 + ni * 16 + lr;
          of[(size_t)m * 1024 + n] = acc[mi][ni][r];
        }
      }
  }
}

// ---------------- compressive memory ----------------

__global__ __launch_bounds__(256) void k_mem(const u16* __restrict__ K, const u16* __restrict__ Vt,
                                             float* __restrict__ Mp, float* __restrict__ zp) {
  __shared__ __align__(16) float sk[128 * 64];
  __shared__ __align__(16) float vv[128 * 64];
  const int bid = blockIdx.x;
  const int g = bid >> 7, h = (bid >> 3) & 15, c = bid & 7;
  const int bh = (g * 8 + c) * 16 + h;
  const u16* kp = K + (size_t)bh * 512 * 64;
  const u16* vp = Vt + (size_t)bh * 64 * 512;
  const int t = threadIdx.x;
  const int d = t & 63, eg = t >> 6;
  float acc[16];
#pragma unroll
  for (int j = 0; j < 16; ++j) acc[j] = 0.f;
  float zacc = 0.f;

  for (int s0 = 0; s0 < 512; s0 += 128) {
    __syncthreads();
    for (int j = 0; j < 32; ++j) {
      int idx = j * 256 + t;
      int ss = idx >> 6, dd = idx & 63;
      sk[idx] = elu1(bf2f(kp[(size_t)(s0 + ss) * 64 + dd]));
      int ee = idx >> 7, s2 = idx & 127;
      vv[s2 * 64 + ee] = bf2f(vp[(size_t)ee * 512 + s0 + s2]);
    }
    __syncthreads();
    for (int ss = 0; ss < 128; ++ss) {
      float a = sk[ss * 64 + d];
      if (eg == 0) zacc += a;
      const f32x4* vr = reinterpret_cast<const f32x4*>(&vv[ss * 64 + eg * 16]);
#pragma unroll
      for (int j4 = 0; j4 < 4; ++j4) {
        f32x4 vq = vr[j4];
        acc[j4 * 4 + 0] += a * vq[0];
        acc[j4 * 4 + 1] += a * vq[1];
        acc[j4 * 4 + 2] += a * vq[2];
        acc[j4 * 4 + 3] += a * vq[3];
      }
    }
  }
  float* mp = Mp + (size_t)bid * 4096 + d * 64 + eg * 16;
#pragma unroll
  for (int j = 0; j < 16; ++j) mp[j] = acc[j];
  if (eg == 0) zp[(size_t)bid * 64 + d] = zacc;
}

__global__ __launch_bounds__(256) void k_red(const float* __restrict__ Mp, const float* __restrict__ zp,
                                             u16* __restrict__ Mt, float* __restrict__ zv) {
  const int gh = blockIdx.x;
  const int t = threadIdx.x;
#pragma unroll
  for (int j = 0; j < 16; ++j) {
    int idx = j * 256 + t;
    int d = idx >> 6, e = idx & 63;
    float s = 0.f;
#pragma unroll
    for (int c = 0; c < 8; ++c) s += Mp[(size_t)(gh * 8 + c) * 4096 + idx];
    Mt[(size_t)gh * 4096 + e * 64 + d] = f2bf(s);
  }
  if (t < 64) {
    float s = 0.f;
#pragma unroll
    for (int c = 0; c < 8; ++c) s += zp[(size_t)(gh * 8 + c) * 64 + t];
    zv[gh * 64 + t] = s;
  }
}

// ---------------- fused attention, flash-style (k-outer, no rescale) ----------------
// grid: ((b,h) * 4 q-groups) = 2048 blocks; 4 waves, wave w owns 32 q-rows.
// LDS ~37KB -> 4 blocks/CU. K/V staged once per block via global_load_lds with
// pre-swizzled source + XOR-swizzled reads (16B-unit swizzle: unit ^= row&7).

__global__ __launch_bounds__(256, 4) void k_attn(const u16* __restrict__ Q, const u16* __restrict__ K,
                                                 const u16* __restrict__ Vt, const u16* __restrict__ Mt,
                                                 const float* __restrict__ zv, const float* __restrict__ bias,
                                                 const float* __restrict__ beta, u16* __restrict__ blend) {
  __shared__ __align__(16) u16 lK[64 * 64];   // K-tile: row k (64) x d (64), swizzled
  __shared__ __align__(16) u16 lV[64 * 64];   // V^T-tile: row e (64) x k (64), swizzled
  __shared__ __align__(16) u16 ps[4][32 * 64]; // per-wave P: row q (32) x k (64), swizzled
  __shared__ float lbias[1023];
  __shared__ float zs[64];
  __shared__ float rsl[4][32];
  __shared__ float dnl[4][32];

  const int bid = blockIdx.x;
  const int bh = bid >> 2, qg = bid & 3;
  const int b = bh >> 4, h = bh & 15, g = b >> 3;
  const int gh = g * 16 + h;
  const int t = threadIdx.x, lane = t & 63, w = t >> 6;
  const int lr = lane & 15, lg = lane >> 4;
  const int q0w = qg * 128 + w * 32;
  const u16* qp = Q + (size_t)bh * 512 * 64;
  const u16* kp = K + (size_t)bh * 512 * 64;
  const u16* vp = Vt + (size_t)bh * 64 * 512;
  const u16* mp = Mt + (size_t)gh * 4096;
  const float gate = 1.f / (1.f + __expf(-beta[h]));
  u16* psw = &ps[w][0];

  // stage bias row + z
  for (int i = t; i < 1023; i += 256) lbias[i] = bias[h * 1023 + i];
  if (t < 64) zs[t] = zv[gh * 64 + t];

  // Q fragments (held all loop): qf[qs][dc] = Q[q0w+qs*16+lr][dc*32+lg*8 ..+8]
  u16x8 qf[2][2];
#pragma unroll
  for (int qs = 0; qs < 2; ++qs)
#pragma unroll
    for (int dc = 0; dc < 2; ++dc)
      qf[qs][dc] = ld8u(qp + (size_t)(q0w + qs * 16 + lr) * 64 + dc * 32 + lg * 8);

  // stage tile 0 (chunk c: 16B unit; row=c>>3, unit=c&7; src d-chunk = unit^(row&7))
#pragma unroll
  for (int i = 0; i < 2; ++i) {
    int c = w * 128 + i * 64 + lane;
    int kr = c >> 3, u = c & 7;
    async16(lK + c * 8, kp + (size_t)kr * 64 + ((u ^ (kr & 7)) << 3));
    async16(lV + c * 8, vp + (size_t)kr * 512 + ((u ^ (kr & 7)) << 3));
  }
  __syncthreads();

  // dens (mem-path denominator), per-wave private
#pragma unroll
  for (int qs = 0; qs < 2; ++qs) {
    float sum = 0.f;
#pragma unroll
    for (int dc = 0; dc < 2; ++dc)
#pragma unroll
      for (int j = 0; j < 8; ++j)
        sum += elu1(bf2f(qf[qs][dc][j])) * zs[dc * 32 + lg * 8 + j];
    sum += __shfl_xor(sum, 16, 64);
    sum += __shfl_xor(sum, 32, 64);
    if (lane < 16) dnl[w][qs * 16 + lane] = sum + 1e-6f;
  }

  f32x4 acc[2][4];
#pragma unroll
  for (int qs = 0; qs < 2; ++qs)
#pragma unroll
    for (int es = 0; es < 4; ++es) acc[qs][es] = (f32x4){0.f, 0.f, 0.f, 0.f};
  float rs[2] = {0.f, 0.f};

  for (int kt = 0; kt < 8; ++kt) {
    // --- QK^T (swapped: mfma(K,Q) -> S^T), exp, pack to ps ---
#pragma unroll
    for (int ks = 0; ks < 4; ++ks) {
      const int kr = ks * 16 + lr;
      u16x8 kf0 = ld8u(lK + kr * 64 + (((0 * 4 + lg) ^ (kr & 7)) << 3));
      u16x8 kf1 = ld8u(lK + kr * 64 + (((1 * 4 + lg) ^ (kr & 7)) << 3));
#pragma unroll
      for (int qs = 0; qs < 2; ++qs) {
        f32x4 s = mfma16(kf0, qf[qs][0], (f32x4){0.f, 0.f, 0.f, 0.f});
        s = mfma16(kf1, qf[qs][1], s);
        const int bbase = kt * 64 + ks * 16 + lg * 4 - (q0w + qs * 16 + lr) + 511;
        u16x4 pk;
        float lsum = 0.f;
#pragma unroll
        for (int r = 0; r < 4; ++r) {
          float p = __expf(s[r] + lbias[bbase + r]);
          lsum += p;
          pk[r] = f2bf(p);
        }
        rs[qs] += lsum;
        const int row = qs * 16 + lr;
        const int addr = row * 64 + (((ks * 2 + (lg >> 1)) ^ (row & 7)) << 3) + (lg & 1) * 4;
        *reinterpret_cast<u16x4*>(psw + addr) = pk;
      }
    }
    // --- PV (A = P from ps, B = V^T tile) ---
#pragma unroll
    for (int kc = 0; kc < 2; ++kc) {
      u16x8 pf[2];
#pragma unroll
      for (int qs = 0; qs < 2; ++qs) {
        const int row = qs * 16 + lr;
        pf[qs] = ld8u(psw + row * 64 + (((kc * 4 + lg) ^ (row & 7)) << 3));
      }
#pragma unroll
      for (int es = 0; es < 4; ++es) {
        const int er = es * 16 + lr;
        u16x8 vf = ld8u(lV + er * 64 + (((kc * 4 + lg) ^ (er & 7)) << 3));
#pragma unroll
        for (int qs = 0; qs < 2; ++qs) acc[qs][es] = mfma16(pf[qs], vf, acc[qs][es]);
      }
    }
    __syncthreads();  // all waves done reading lK/lV
    if (kt + 1 < 8) {
#pragma unroll
      for (int i = 0; i < 2; ++i) {
        int c = w * 128 + i * 64 + lane;
        int kr = c >> 3, u = c & 7;
        async16(lK + c * 8, kp + (size_t)((kt + 1) * 64 + kr) * 64 + ((u ^ (kr & 7)) << 3));
        async16(lV + c * 8, vp + (size_t)kr * 512 + (kt + 1) * 64 + ((u ^ (kr & 7)) << 3));
      }
    }
    __syncthreads();  // stages complete (vmcnt drained per-wave before barrier)
  }

  // rowsums -> 1/sum in per-wave LDS
#pragma unroll
  for (int qs = 0; qs < 2; ++qs) {
    float v = rs[qs];
    v += __shfl_xor(v, 16, 64);
    v += __shfl_xor(v, 32, 64);
    if (lane < 16) rsl[w][qs * 16 + lane] = 1.f / v;
  }

  // compressive-memory matmul: am = (elu(q)+1) @ M^T
  u16x8 sqf[2][2];
#pragma unroll
  for (int qs = 0; qs < 2; ++qs)
#pragma unroll
    for (int dc = 0; dc < 2; ++dc)
#pragma unroll
      for (int j = 0; j < 8; ++j) sqf[qs][dc][j] = f2bf(elu1(bf2f(qf[qs][dc][j])));
  f32x4 am[2][4];
#pragma unroll
  for (int qs = 0; qs < 2; ++qs)
#pragma unroll
    for (int es = 0; es < 4; ++es) am[qs][es] = (f32x4){0.f, 0.f, 0.f, 0.f};
#pragma unroll
  for (int es = 0; es < 4; ++es)
#pragma unroll
    for (int dc = 0; dc < 2; ++dc) {
      u16x8 mf = ld8u(mp + (es * 16 + lr) * 64 + dc * 32 + lg * 8);
#pragma unroll
      for (int qs = 0; qs < 2; ++qs) am[qs][es] = mfma16(sqf[qs][dc], mf, am[qs][es]);
    }

  // blend + store
#pragma unroll
  for (int qs = 0; qs < 2; ++qs)
#pragma unroll
    for (int r = 0; r < 4; ++r) {
      const int rowl = qs * 16 + lg * 4 + r;
      const float rinv = rsl[w][rowl];
      const float den = dnl[w][rowl];
      const int q = q0w + rowl;
#pragma unroll
      for (int es = 0; es < 4; ++es) {
        float o = gate * (am[qs][es][r] / den) + (1.f - gate) * acc[qs][es][r] * rinv;
        blend[(size_t)(b * 512 + q) * 1024 + h * 64 + es * 16 + lr] = f2bf(o);
      }
    }
}

// ---------------- launch ----------------

extern "C" void kernel_launch(void* const* d_in, const int* in_sizes, int n_in,
                              void* d_out, int out_size, void* d_ws, size_t ws_size,
                              hipStream_t stream) {
  (void)in_sizes; (void)n_in; (void)out_size; (void)ws_size;
  const float* hs   = (const float*)d_in[0];
  const float* Wq   = (const float*)d_in[1];
  const float* Wk   = (const float*)d_in[2];
  const float* Wv   = (const float*)d_in[3];
  const float* Wo   = (const float*)d_in[4];
  const float* rel  = (const float*)d_in[5];
  const float* beta = (const float*)d_in[6];
  float* out = (float*)d_out;

  char* ws = (char*)d_ws;
  size_t off = 0;
  auto alloc = [&](size_t bytes) -> char* {
    char* p = ws + off;
    off += (bytes + 255) & ~(size_t)255;
    return p;
  };
  u16* hsb    = (u16*)alloc(16384ull * 1024 * 2);  // reused as blend after GEMM1
  u16* wt     = (u16*)alloc(3072ull * 1024 * 2);
  u16* wot    = (u16*)alloc(1024ull * 1024 * 2);
  u16* q      = (u16*)alloc(16384ull * 1024 * 2);
  u16* k      = (u16*)alloc(16384ull * 1024 * 2);
  u16* vt     = (u16*)alloc(16384ull * 1024 * 2);
  float* Mp   = (float*)alloc(512ull * 4096 * 4);
  float* zp   = (float*)alloc(512ull * 64 * 4);
  u16* Mt     = (u16*)alloc(64ull * 4096 * 2);
  float* zv   = (float*)alloc(64ull * 64 * 4);
  float* bias = (float*)alloc(16ull * 1023 * 4);
  u16* blend  = hsb;

  k_cvt<<<8192, 256, 0, stream>>>(hs, hsb);
  k_tr<<<4096, 1024, 0, stream>>>(Wq, Wk, Wv, Wo, wt, wot);
  k_bias<<<4, 256, 0, stream>>>(rel, bias);
  k_gemm<0><<<dim3(128, 24), 256, 0, stream>>>(hsb, wt, q, k, vt, nullptr);
  k_mem<<<512, 256, 0, stream>>>(k, vt, Mp, zp);
  k_red<<<64, 256, 0, stream>>>(Mp, zp, Mt, zv);
  k_attn<<<2048, 256, 0, stream>>>(q, k, vt, Mt, zv, bias, beta, blend);
  k_gemm<1><<<dim3(128, 8), 256, 0, stream>>>(blend, wot, nullptr, nullptr, nullptr, out);
}

// Round 3
// 401.345 us; speedup vs baseline: 1.5574x; 1.0954x over previous
//
#include <hip/hip_runtime.h>
#include <stdint.h>

typedef unsigned short u16;
typedef u16 u16x8 __attribute__((ext_vector_type(8)));
typedef u16 u16x4 __attribute__((ext_vector_type(4)));
typedef __bf16 bf16x8 __attribute__((ext_vector_type(8)));
typedef float f32x4 __attribute__((ext_vector_type(4)));

#define DEV static __device__ __forceinline__

DEV u16 f2bf(float f) {
  union { float f; uint32_t u; } v; v.f = f;
  uint32_t r = v.u + 0x7FFFu + ((v.u >> 16) & 1u);
  return (u16)(r >> 16);
}
DEV float bf2f(u16 s) {
  union { uint32_t u; float f; } v; v.u = ((uint32_t)s) << 16;
  return v.f;
}
DEV float elu1(float x) { return x > 0.f ? x + 1.f : __expf(x); }
DEV u16x8 ld8u(const u16* p) { return *reinterpret_cast<const u16x8*>(p); }

DEV f32x4 mfma16(u16x8 a, u16x8 b, f32x4 c) {
  return __builtin_amdgcn_mfma_f32_16x16x32_bf16(
      __builtin_bit_cast(bf16x8, a), __builtin_bit_cast(bf16x8, b), c, 0, 0, 0);
}
DEV void async16(void* lds, const void* g) {
  __builtin_amdgcn_global_load_lds(
      (__attribute__((address_space(1))) void*)g,
      (__attribute__((address_space(3))) void*)lds, 16, 0, 0);
}

// ---------------- prep kernels ----------------

__global__ __launch_bounds__(256) void k_cvt(const float* __restrict__ in, u16* __restrict__ out) {
  int i = blockIdx.x * 256 + threadIdx.x;
  const float4* p = reinterpret_cast<const float4*>(in) + (size_t)i * 2;
  float4 a = p[0], b = p[1];
  u16x8 o;
  o[0] = f2bf(a.x); o[1] = f2bf(a.y); o[2] = f2bf(a.z); o[3] = f2bf(a.w);
  o[4] = f2bf(b.x); o[5] = f2bf(b.y); o[6] = f2bf(b.z); o[7] = f2bf(b.w);
  reinterpret_cast<u16x8*>(out)[i] = o;
}

__global__ __launch_bounds__(1024) void k_tr(const float* __restrict__ Wq, const float* __restrict__ Wk,
                                             const float* __restrict__ Wv, const float* __restrict__ Wo,
                                             u16* __restrict__ wt, u16* __restrict__ wot) {
  __shared__ float tb[32][33];
  int mat = blockIdx.x >> 10;
  int tile = blockIdx.x & 1023;
  int n0 = (tile >> 5) * 32;
  int k0 = (tile & 31) * 32;
  const float* W = (mat == 0) ? Wq : (mat == 1) ? Wk : (mat == 2) ? Wv : Wo;
  int tx = threadIdx.x & 31, ty = threadIdx.x >> 5;
  tb[ty][tx] = W[(size_t)(k0 + ty) * 1024 + n0 + tx];
  __syncthreads();
  u16 v = f2bf(tb[tx][ty]);
  if (mat < 3) wt[(size_t)(mat * 1024 + n0 + ty) * 1024 + k0 + tx] = v;
  else         wot[(size_t)(n0 + ty) * 1024 + k0 + tx] = v;
}

__global__ void k_bias(const float* __restrict__ rel, float* __restrict__ bias) {
  int off = blockIdx.x * 256 + threadIdx.x;
  if (off >= 1023) return;
  int rp = off - 511;
  int bck = rp > 0 ? 16 : 0;
  int arp = rp < 0 ? -rp : rp;
  int idx;
  if (arp < 8) idx = arp;
  else {
    float l = logf((float)arp * 0.125f) / logf(16.0f) * 8.0f;
    int lg = 8 + (int)l;
    idx = lg < 15 ? lg : 15;
  }
  bck += idx;
  for (int h = 0; h < 16; ++h) bias[h * 1023 + off] = rel[bck * 16 + h];
}

// ---------------- 256x256 pipelined MFMA GEMM ----------------
// 8 waves (2M x 4N), BK=64, double-buffered 128KiB LDS, global_load_lds
// width-16 with pre-swizzled source (16B unit ^= row&7), counted vmcnt(8)
// (never drained in steady state), raw s_barrier, setprio around MFMA.
// K fixed at 1024 (16 K-tiles). Grid is 1D with bijective XCD swizzle.
// EPI=0: C = hs @ [Wq|Wk|Wv] -> scatter Q(b,h,s,d), K(b,h,s,d), Vt(b,h,d,s)
// EPI=1: C = blend @ Wo -> fp32 out

template <int EPI, int NBN, int CPX>
__global__ __launch_bounds__(512, 2) void k_g256(const u16* __restrict__ A, const u16* __restrict__ Bt,
                                                 u16* __restrict__ oq, u16* __restrict__ ok2,
                                                 u16* __restrict__ ovt, float* __restrict__ of) {
  __shared__ __align__(16) u16 lsA[2][256 * 64];
  __shared__ __align__(16) u16 lsB[2][256 * 64];
  const int t = threadIdx.x;
  const int lane = t & 63, w = t >> 6;
  const int wm = w >> 2, wn = w & 3;
  const int lr = lane & 15, lg = lane >> 4;

  // bijective XCD swizzle (grid % 8 == 0), n-fast linear order
  const int bid = blockIdx.x;
  const int wg = (bid & 7) * CPX + (bid >> 3);
  const int m0 = (wg / NBN) * 256;
  const int n0 = (wg % NBN) * 256;

  auto stage = [&](int kt, int slot) {
    const int k0 = kt * 64;
#pragma unroll
    for (int i = 0; i < 4; ++i) {
      int c = i * 512 + t;
      int row = c >> 3, u = c & 7;
      int us = (u ^ (row & 7)) << 3;
      async16(&lsA[slot][c * 8], A + (size_t)(m0 + row) * 1024 + k0 + us);
      async16(&lsB[slot][c * 8], Bt + (size_t)(n0 + row) * 1024 + k0 + us);
    }
  };

  f32x4 acc[8][4];
#pragma unroll
  for (int i = 0; i < 8; ++i)
#pragma unroll
    for (int j = 0; j < 4; ++j) acc[i][j] = (f32x4){0.f, 0.f, 0.f, 0.f};

  stage(0, 0);
  stage(1, 1);
  asm volatile("s_waitcnt vmcnt(8)" ::: "memory");  // tile 0 landed, tile 1 in flight
  __builtin_amdgcn_s_barrier();

  for (int kt = 0; kt < 16; ++kt) {
    const int slot = kt & 1;
    const u16* la = &lsA[slot][0];
    const u16* lb = &lsB[slot][0];

    u16x8 bf[4][2], af[4][2];
#pragma unroll
    for (int ni = 0; ni < 4; ++ni) {
      const int r = wn * 64 + ni * 16 + lr;
#pragma unroll
      for (int kk = 0; kk < 2; ++kk)
        bf[ni][kk] = ld8u(lb + r * 64 + (((kk * 4 + lg) ^ (r & 7)) << 3));
    }
#pragma unroll
    for (int mi = 0; mi < 4; ++mi) {
      const int r = wm * 128 + mi * 16 + lr;
#pragma unroll
      for (int kk = 0; kk < 2; ++kk)
        af[mi][kk] = ld8u(la + r * 64 + (((kk * 4 + lg) ^ (r & 7)) << 3));
    }
    __builtin_amdgcn_s_setprio(1);
#pragma unroll
    for (int mi = 0; mi < 4; ++mi)
#pragma unroll
      for (int ni = 0; ni < 4; ++ni)
#pragma unroll
        for (int kk = 0; kk < 2; ++kk)
          acc[mi][ni] = mfma16(af[mi][kk], bf[ni][kk], acc[mi][ni]);
    __builtin_amdgcn_s_setprio(0);

    u16x8 af2[4][2];
#pragma unroll
    for (int mi = 0; mi < 4; ++mi) {
      const int r = wm * 128 + 64 + mi * 16 + lr;
#pragma unroll
      for (int kk = 0; kk < 2; ++kk)
        af2[mi][kk] = ld8u(la + r * 64 + (((kk * 4 + lg) ^ (r & 7)) << 3));
    }
    // all my ds_reads of this slot complete -> barrier -> safe to overwrite slot
    asm volatile("s_waitcnt lgkmcnt(0)" ::: "memory");
    __builtin_amdgcn_s_barrier();
    if (kt + 2 < 16) stage(kt + 2, slot);

    __builtin_amdgcn_s_setprio(1);
#pragma unroll
    for (int mi = 0; mi < 4; ++mi)
#pragma unroll
      for (int ni = 0; ni < 4; ++ni)
#pragma unroll
        for (int kk = 0; kk < 2; ++kk)
          acc[4 + mi][ni] = mfma16(af2[mi][kk], bf[ni][kk], acc[4 + mi][ni]);
    __builtin_amdgcn_s_setprio(0);

    if (kt + 2 < 16) { asm volatile("s_waitcnt vmcnt(8)" ::: "memory"); }  // kt+1 landed
    else             { asm volatile("s_waitcnt vmcnt(0)" ::: "memory"); }
    __builtin_amdgcn_s_barrier();
  }

  if (EPI == 0) {
    const int which = n0 >> 10;
    const int nb = (n0 & 1023) + wn * 64;
#pragma unroll
    for (int mi = 0; mi < 8; ++mi)
#pragma unroll
      for (int r = 0; r < 4; ++r) {
        int m = m0 + wm * 128 + mi * 16 + lg * 4 + r;
        int b = m >> 9, s = m & 511;
#pragma unroll
        for (int ni = 0; ni < 4; ++ni) {
          int nc = nb + ni * 16 + lr;
          int h = nc >> 6, d = nc & 63;
          int bh = b * 16 + h;
          u16 v = f2bf(acc[mi][ni][r]);
          if (which == 0)      oq[(size_t)(bh * 512 + s) * 64 + d] = v;
          else if (which == 1) ok2[(size_t)(bh * 512 + s) * 64 + d] = v;
          else                 ovt[(size_t)(bh * 64 + d) * 512 + s] = v;
        }
      }
  } else {
#pragma unroll
    for (int mi = 0; mi < 8; ++mi)
#pragma unroll
      for (int r = 0; r < 4; ++r) {
        int m = m0 + wm * 128 + mi * 16 + lg * 4 + r;
#pragma unroll
        for (int ni = 0; ni < 4; ++ni) {
          int n = n0 + wn * 64 + ni * 16 + lr;
          of[(size_t)m * 1024 + n] = acc[mi][ni][r];
        }
      }
  }
}

// ---------------- compressive memory ----------------

__global__ __launch_bounds__(256) void k_mem(const u16* __restrict__ K, const u16* __restrict__ Vt,
                                             float* __restrict__ Mp, float* __restrict__ zp) {
  __shared__ __align__(16) float sk[128 * 64];
  __shared__ __align__(16) float vv[128 * 64];
  const int bid = blockIdx.x;
  const int g = bid >> 7, h = (bid >> 3) & 15, c = bid & 7;
  const int bh = (g * 8 + c) * 16 + h;
  const u16* kp = K + (size_t)bh * 512 * 64;
  const u16* vp = Vt + (size_t)bh * 64 * 512;
  const int t = threadIdx.x;
  const int d = t & 63, eg = t >> 6;
  float acc[16];
#pragma unroll
  for (int j = 0; j < 16; ++j) acc[j] = 0.f;
  float zacc = 0.f;

  for (int s0 = 0; s0 < 512; s0 += 128) {
    __syncthreads();
    for (int j = 0; j < 32; ++j) {
      int idx = j * 256 + t;
      int ss = idx >> 6, dd = idx & 63;
      sk[idx] = elu1(bf2f(kp[(size_t)(s0 + ss) * 64 + dd]));
      int ee = idx >> 7, s2 = idx & 127;
      vv[s2 * 64 + ee] = bf2f(vp[(size_t)ee * 512 + s0 + s2]);
    }
    __syncthreads();
    for (int ss = 0; ss < 128; ++ss) {
      float a = sk[ss * 64 + d];
      if (eg == 0) zacc += a;
      const f32x4* vr = reinterpret_cast<const f32x4*>(&vv[ss * 64 + eg * 16]);
#pragma unroll
      for (int j4 = 0; j4 < 4; ++j4) {
        f32x4 vq = vr[j4];
        acc[j4 * 4 + 0] += a * vq[0];
        acc[j4 * 4 + 1] += a * vq[1];
        acc[j4 * 4 + 2] += a * vq[2];
        acc[j4 * 4 + 3] += a * vq[3];
      }
    }
  }
  float* mp = Mp + (size_t)bid * 4096 + d * 64 + eg * 16;
#pragma unroll
  for (int j = 0; j < 16; ++j) mp[j] = acc[j];
  if (eg == 0) zp[(size_t)bid * 64 + d] = zacc;
}

__global__ __launch_bounds__(256) void k_red(const float* __restrict__ Mp, const float* __restrict__ zp,
                                             u16* __restrict__ Mt, float* __restrict__ zv) {
  const int gh = blockIdx.x;
  const int t = threadIdx.x;
#pragma unroll
  for (int j = 0; j < 16; ++j) {
    int idx = j * 256 + t;
    int d = idx >> 6, e = idx & 63;
    float s = 0.f;
#pragma unroll
    for (int c = 0; c < 8; ++c) s += Mp[(size_t)(gh * 8 + c) * 4096 + idx];
    Mt[(size_t)gh * 4096 + e * 64 + d] = f2bf(s);
  }
  if (t < 64) {
    float s = 0.f;
#pragma unroll
    for (int c = 0; c < 8; ++c) s += zp[(size_t)(gh * 8 + c) * 64 + t];
    zv[gh * 64 + t] = s;
  }
}

// ---------------- fused attention, flash-style (k-outer, no rescale) ----------------

__global__ __launch_bounds__(256, 4) void k_attn(const u16* __restrict__ Q, const u16* __restrict__ K,
                                                 const u16* __restrict__ Vt, const u16* __restrict__ Mt,
                                                 const float* __restrict__ zv, const float* __restrict__ bias,
                                                 const float* __restrict__ beta, u16* __restrict__ blend) {
  __shared__ __align__(16) u16 lK[64 * 64];
  __shared__ __align__(16) u16 lV[64 * 64];
  __shared__ __align__(16) u16 ps[4][32 * 64];
  __shared__ float lbias[1023];
  __shared__ float zs[64];
  __shared__ float rsl[4][32];
  __shared__ float dnl[4][32];

  const int bid = blockIdx.x;
  const int bh = bid >> 2, qg = bid & 3;
  const int b = bh >> 4, h = bh & 15, g = b >> 3;
  const int gh = g * 16 + h;
  const int t = threadIdx.x, lane = t & 63, w = t >> 6;
  const int lr = lane & 15, lg = lane >> 4;
  const int q0w = qg * 128 + w * 32;
  const u16* qp = Q + (size_t)bh * 512 * 64;
  const u16* kp = K + (size_t)bh * 512 * 64;
  const u16* vp = Vt + (size_t)bh * 64 * 512;
  const u16* mp = Mt + (size_t)gh * 4096;
  const float gate = 1.f / (1.f + __expf(-beta[h]));
  u16* psw = &ps[w][0];

  for (int i = t; i < 1023; i += 256) lbias[i] = bias[h * 1023 + i];
  if (t < 64) zs[t] = zv[gh * 64 + t];

  u16x8 qf[2][2];
#pragma unroll
  for (int qs = 0; qs < 2; ++qs)
#pragma unroll
    for (int dc = 0; dc < 2; ++dc)
      qf[qs][dc] = ld8u(qp + (size_t)(q0w + qs * 16 + lr) * 64 + dc * 32 + lg * 8);

#pragma unroll
  for (int i = 0; i < 2; ++i) {
    int c = w * 128 + i * 64 + lane;
    int kr = c >> 3, u = c & 7;
    async16(lK + c * 8, kp + (size_t)kr * 64 + ((u ^ (kr & 7)) << 3));
    async16(lV + c * 8, vp + (size_t)kr * 512 + ((u ^ (kr & 7)) << 3));
  }
  __syncthreads();

#pragma unroll
  for (int qs = 0; qs < 2; ++qs) {
    float sum = 0.f;
#pragma unroll
    for (int dc = 0; dc < 2; ++dc)
#pragma unroll
      for (int j = 0; j < 8; ++j)
        sum += elu1(bf2f(qf[qs][dc][j])) * zs[dc * 32 + lg * 8 + j];
    sum += __shfl_xor(sum, 16, 64);
    sum += __shfl_xor(sum, 32, 64);
    if (lane < 16) dnl[w][qs * 16 + lane] = sum + 1e-6f;
  }

  f32x4 acc[2][4];
#pragma unroll
  for (int qs = 0; qs < 2; ++qs)
#pragma unroll
    for (int es = 0; es < 4; ++es) acc[qs][es] = (f32x4){0.f, 0.f, 0.f, 0.f};
  float rs[2] = {0.f, 0.f};

  for (int kt = 0; kt < 8; ++kt) {
#pragma unroll
    for (int ks = 0; ks < 4; ++ks) {
      const int kr = ks * 16 + lr;
      u16x8 kf0 = ld8u(lK + kr * 64 + (((0 * 4 + lg) ^ (kr & 7)) << 3));
      u16x8 kf1 = ld8u(lK + kr * 64 + (((1 * 4 + lg) ^ (kr & 7)) << 3));
#pragma unroll
      for (int qs = 0; qs < 2; ++qs) {
        f32x4 s = mfma16(kf0, qf[qs][0], (f32x4){0.f, 0.f, 0.f, 0.f});
        s = mfma16(kf1, qf[qs][1], s);
        const int bbase = kt * 64 + ks * 16 + lg * 4 - (q0w + qs * 16 + lr) + 511;
        u16x4 pk;
        float lsum = 0.f;
#pragma unroll
        for (int r = 0; r < 4; ++r) {
          float p = __expf(s[r] + lbias[bbase + r]);
          lsum += p;
          pk[r] = f2bf(p);
        }
        rs[qs] += lsum;
        const int row = qs * 16 + lr;
        const int addr = row * 64 + (((ks * 2 + (lg >> 1)) ^ (row & 7)) << 3) + (lg & 1) * 4;
        *reinterpret_cast<u16x4*>(psw + addr) = pk;
      }
    }
#pragma unroll
    for (int kc = 0; kc < 2; ++kc) {
      u16x8 pf[2];
#pragma unroll
      for (int qs = 0; qs < 2; ++qs) {
        const int row = qs * 16 + lr;
        pf[qs] = ld8u(psw + row * 64 + (((kc * 4 + lg) ^ (row & 7)) << 3));
      }
#pragma unroll
      for (int es = 0; es < 4; ++es) {
        const int er = es * 16 + lr;
        u16x8 vf = ld8u(lV + er * 64 + (((kc * 4 + lg) ^ (er & 7)) << 3));
#pragma unroll
        for (int qs = 0; qs < 2; ++qs) acc[qs][es] = mfma16(pf[qs], vf, acc[qs][es]);
      }
    }
    __syncthreads();
    if (kt + 1 < 8) {
#pragma unroll
      for (int i = 0; i < 2; ++i) {
        int c = w * 128 + i * 64 + lane;
        int kr = c >> 3, u = c & 7;
        async16(lK + c * 8, kp + (size_t)((kt + 1) * 64 + kr) * 64 + ((u ^ (kr & 7)) << 3));
        async16(lV + c * 8, vp + (size_t)kr * 512 + (kt + 1) * 64 + ((u ^ (kr & 7)) << 3));
      }
    }
    __syncthreads();
  }

#pragma unroll
  for (int qs = 0; qs < 2; ++qs) {
    float v = rs[qs];
    v += __shfl_xor(v, 16, 64);
    v += __shfl_xor(v, 32, 64);
    if (lane < 16) rsl[w][qs * 16 + lane] = 1.f / v;
  }

  u16x8 sqf[2][2];
#pragma unroll
  for (int qs = 0; qs < 2; ++qs)
#pragma unroll
    for (int dc = 0; dc < 2; ++dc)
#pragma unroll
      for (int j = 0; j < 8; ++j) sqf[qs][dc][j] = f2bf(elu1(bf2f(qf[qs][dc][j])));
  f32x4 am[2][4];
#pragma unroll
  for (int qs = 0; qs < 2; ++qs)
#pragma unroll
    for (int es = 0; es < 4; ++es) am[qs][es] = (f32x4){0.f, 0.f, 0.f, 0.f};
#pragma unroll
  for (int es = 0; es < 4; ++es)
#pragma unroll
    for (int dc = 0; dc < 2; ++dc) {
      u16x8 mf = ld8u(mp + (es * 16 + lr) * 64 + dc * 32 + lg * 8);
#pragma unroll
      for (int qs = 0; qs < 2; ++qs) am[qs][es] = mfma16(sqf[qs][dc], mf, am[qs][es]);
    }

#pragma unroll
  for (int qs = 0; qs < 2; ++qs)
#pragma unroll
    for (int r = 0; r < 4; ++r) {
      const int rowl = qs * 16 + lg * 4 + r;
      const float rinv = rsl[w][rowl];
      const float den = dnl[w][rowl];
      const int q = q0w + rowl;
#pragma unroll
      for (int es = 0; es < 4; ++es) {
        float o = gate * (am[qs][es][r] / den) + (1.f - gate) * acc[qs][es][r] * rinv;
        blend[(size_t)(b * 512 + q) * 1024 + h * 64 + es * 16 + lr] = f2bf(o);
      }
    }
}

// ---------------- launch ----------------

extern "C" void kernel_launch(void* const* d_in, const int* in_sizes, int n_in,
                              void* d_out, int out_size, void* d_ws, size_t ws_size,
                              hipStream_t stream) {
  (void)in_sizes; (void)n_in; (void)out_size; (void)ws_size;
  const float* hs   = (const float*)d_in[0];
  const float* Wq   = (const float*)d_in[1];
  const float* Wk   = (const float*)d_in[2];
  const float* Wv   = (const float*)d_in[3];
  const float* Wo   = (const float*)d_in[4];
  const float* rel  = (const float*)d_in[5];
  const float* beta = (const float*)d_in[6];
  float* out = (float*)d_out;

  char* ws = (char*)d_ws;
  size_t off = 0;
  auto alloc = [&](size_t bytes) -> char* {
    char* p = ws + off;
    off += (bytes + 255) & ~(size_t)255;
    return p;
  };
  u16* hsb    = (u16*)alloc(16384ull * 1024 * 2);  // reused as blend after GEMM1
  u16* wt     = (u16*)alloc(3072ull * 1024 * 2);
  u16* wot    = (u16*)alloc(1024ull * 1024 * 2);
  u16* q      = (u16*)alloc(16384ull * 1024 * 2);
  u16* k      = (u16*)alloc(16384ull * 1024 * 2);
  u16* vt     = (u16*)alloc(16384ull * 1024 * 2);
  float* Mp   = (float*)alloc(512ull * 4096 * 4);
  float* zp   = (float*)alloc(512ull * 64 * 4);
  u16* Mt     = (u16*)alloc(64ull * 4096 * 2);
  float* zv   = (float*)alloc(64ull * 64 * 4);
  float* bias = (float*)alloc(16ull * 1023 * 4);
  u16* blend  = hsb;

  k_cvt<<<8192, 256, 0, stream>>>(hs, hsb);
  k_tr<<<4096, 1024, 0, stream>>>(Wq, Wk, Wv, Wo, wt, wot);
  k_bias<<<4, 256, 0, stream>>>(rel, bias);
  // GEMM1: M=16384, N=3072 -> 64x12 = 768 blocks (768%8==0)
  k_g256<0, 12, 96><<<768, 512, 0, stream>>>(hsb, wt, q, k, vt, nullptr);
  k_mem<<<512, 256, 0, stream>>>(k, vt, Mp, zp);
  k_red<<<64, 256, 0, stream>>>(Mp, zp, Mt, zv);
  k_attn<<<2048, 256, 0, stream>>>(q, k, vt, Mt, zv, bias, beta, blend);
  // GEMM2: M=16384, N=1024 -> 64x4 = 256 blocks
  k_g256<1, 4, 32><<<256, 512, 0, stream>>>(blend, wot, nullptr, nullptr, nullptr, out);
}